// Round 1
// baseline (960.290 us; speedup 1.0000x reference)
//
#include <hip/hip_runtime.h>
#include <hip/hip_bf16.h>
#include <stdint.h>

typedef unsigned short ushort;
typedef unsigned int uint;

#define N_NODES 100000
#define N_EDGES 1600000
#define KDIM 192      // 3 * 64 concatenated h_j
#define HIDDEN 512

typedef __attribute__((ext_vector_type(8))) short short8;
typedef __attribute__((ext_vector_type(4))) float float4v;

__device__ __forceinline__ float bf2f(ushort u){
    uint x = ((uint)u) << 16;
    return __builtin_bit_cast(float, x);
}
__device__ __forceinline__ ushort f2bf(float f){
    uint u = __builtin_bit_cast(uint, f);
    u += 0x7fffu + ((u >> 16) & 1u);   // round-to-nearest-even
    return (ushort)(u >> 16);
}

// ---- 1. degree histogram (dst) ----
__global__ void k_deg(const int* __restrict__ dst, int* __restrict__ deg){
    int e = blockIdx.x * 256 + threadIdx.x;
    if (e < N_EDGES) atomicAdd(&deg[dst[e]], 1);
}

// ---- 2. per-node CSR base (block scan + 1 atomic/block), norm ----
__global__ void k_rowptr(const int* __restrict__ deg, int* __restrict__ rowptr,
                         int* __restrict__ cursor, float* __restrict__ nrm,
                         int* __restrict__ counter){
    __shared__ int sc[256];
    __shared__ int sbase;
    int t = threadIdx.x;
    int n = blockIdx.x * 256 + t;
    int d = (n < N_NODES) ? deg[n] : 0;
    sc[t] = d; __syncthreads();
    for (int off = 1; off < 256; off <<= 1){
        int v = 0;
        if (t >= off) v = sc[t - off];
        __syncthreads();
        sc[t] += v;
        __syncthreads();
    }
    int incl = sc[t];
    int total = sc[255];
    int excl = incl - d;
    if (t == 0) sbase = atomicAdd(counter, total);
    __syncthreads();
    if (n < N_NODES){
        int base = sbase + excl;
        rowptr[n] = base;
        cursor[n] = base;
        nrm[n] = rsqrtf((float)(d > 0 ? d : 1));
    }
}

// ---- 3. scatter edges into CSR ----
__global__ void k_scatter(const int* __restrict__ src, const int* __restrict__ dst,
                          int* __restrict__ cursor, int* __restrict__ csr){
    int e = blockIdx.x * 256 + threadIdx.x;
    if (e < N_EDGES){
        int d = dst[e];
        int p = atomicAdd(&cursor[d], 1);
        csr[p] = src[e];
    }
}

// ---- 4. aggregation round: h_out[n] = norm[n] * sum_{s in N(n)} norm[s]*h_in[s] ----
// one wave per node, lane = feature (64)
template<bool F32>
__global__ void k_agg(const void* __restrict__ inp, long istride,
                      ushort* __restrict__ H, int outoff,
                      const int* __restrict__ rowptr, const int* __restrict__ deg,
                      const float* __restrict__ nrm, const int* __restrict__ csr){
    int node = (blockIdx.x << 2) + (threadIdx.x >> 6);
    int lane = threadIdx.x & 63;
    if (node >= N_NODES) return;
    int beg = rowptr[node];
    int d   = deg[node];
    const float*  inF = (const float*)inp;
    const ushort* inB = (const ushort*)inp;
    float acc = 0.f;
    int i = 0;
    for (; i + 4 <= d; i += 4){
        int s0 = csr[beg+i+0], s1 = csr[beg+i+1], s2 = csr[beg+i+2], s3 = csr[beg+i+3];
        float v0, v1, v2, v3;
        if (F32){
            v0 = inF[(long)s0*istride + lane]; v1 = inF[(long)s1*istride + lane];
            v2 = inF[(long)s2*istride + lane]; v3 = inF[(long)s3*istride + lane];
        } else {
            v0 = bf2f(inB[(long)s0*istride + lane]); v1 = bf2f(inB[(long)s1*istride + lane]);
            v2 = bf2f(inB[(long)s2*istride + lane]); v3 = bf2f(inB[(long)s3*istride + lane]);
        }
        float w0 = nrm[s0], w1 = nrm[s1], w2 = nrm[s2], w3 = nrm[s3];
        acc += w0*v0; acc += w1*v1; acc += w2*v2; acc += w3*v3;
    }
    for (; i < d; ++i){
        int s = csr[beg+i];
        float v = F32 ? inF[(long)s*istride + lane] : bf2f(inB[(long)s*istride + lane]);
        acc += nrm[s] * v;
    }
    H[(long)node*KDIM + outoff + lane] = f2bf(nrm[node] * acc);
}

// ---- 5. fold weights: MT[c][64j+d] = sum_k Wj[k,d] * fcW[c, 512j+k]  (bf16, transposed) ----
__global__ void k_prepM(const float* __restrict__ W0, const float* __restrict__ W1,
                        const float* __restrict__ W2, const float* __restrict__ fcW,
                        ushort* __restrict__ MT){
    int c  = blockIdx.x;        // 0..511
    int jd = threadIdx.x;       // 0..191
    int j = jd >> 6, d = jd & 63;
    const float* W  = (j == 0) ? W0 : (j == 1) ? W1 : W2;
    const float* fw = fcW + (long)c*1536 + j*512;
    float s = 0.f;
    #pragma unroll 4
    for (int k = 0; k < 512; ++k) s += W[k*64 + d] * fw[k];
    MT[c*KDIM + jd] = f2bf(s);
}

// ---- 5b. folded bias: Bc[c] = fc_b[c] + sum_j sum_k bj[k]*fcW[c,512j+k] ----
__global__ void k_bias(const float* __restrict__ b0, const float* __restrict__ b1,
                       const float* __restrict__ b2, const float* __restrict__ fcW,
                       const float* __restrict__ fcb, float* __restrict__ Bc){
    int c = blockIdx.x*256 + threadIdx.x;
    if (c >= HIDDEN) return;
    const float* fw = fcW + (long)c*1536;
    float s = fcb[c];
    for (int k = 0; k < 512; ++k)
        s += b0[k]*fw[k] + b1[k]*fw[512+k] + b2[k]*fw[1024+k];
    Bc[c] = s;
}

// ---- 6. GEMM: final[N,512] = H[N,192] @ M[192,512] + Bc  (bf16 MFMA, fp32 acc) ----
#define LDK 104   // padded LDS row stride (ushorts): 16B-aligned, bank-friendly
__global__ __launch_bounds__(256) void k_gemm(const ushort* __restrict__ H,
                                              const ushort* __restrict__ MT,
                                              const float* __restrict__ Bc,
                                              ushort* __restrict__ Fout){
    __shared__ ushort As[128*LDK];
    __shared__ ushort Bs[128*LDK];
    int t = threadIdx.x;
    int n0 = blockIdx.x * 128;
    int c0 = blockIdx.y * 128;
    int w = t >> 6, lane = t & 63;
    int wr = (w >> 1) * 64, wc = (w & 1) * 64;
    int m16 = lane & 15, quad = lane >> 4;
    float4v acc[4][4] = {};
    for (int kc = 0; kc < KDIM; kc += 96){
        #pragma unroll
        for (int it = 0; it < 6; ++it){
            int flat = it*256 + t;          // 0..1535 = 128 rows * 12 segs
            int row = flat / 12, seg = flat % 12;
            int gr = n0 + row;
            short8 av = {0,0,0,0,0,0,0,0};
            if (gr < N_NODES) av = *(const short8*)(H + (long)gr*KDIM + kc + seg*8);
            *(short8*)(As + row*LDK + seg*8) = av;
            short8 bv = *(const short8*)(MT + (long)(c0+row)*KDIM + kc + seg*8);
            *(short8*)(Bs + row*LDK + seg*8) = bv;
        }
        __syncthreads();
        #pragma unroll
        for (int kk = 0; kk < 96; kk += 32){
            short8 af[4], bfr[4];
            #pragma unroll
            for (int i = 0; i < 4; ++i)
                af[i] = *(const short8*)(As + (wr + i*16 + m16)*LDK + kk + quad*8);
            #pragma unroll
            for (int j = 0; j < 4; ++j)
                bfr[j] = *(const short8*)(Bs + (wc + j*16 + m16)*LDK + kk + quad*8);
            #pragma unroll
            for (int i = 0; i < 4; ++i)
                #pragma unroll
                for (int j = 0; j < 4; ++j)
                    acc[i][j] = __builtin_amdgcn_mfma_f32_16x16x32_bf16(af[i], bfr[j], acc[i][j], 0, 0, 0);
        }
        __syncthreads();
    }
    #pragma unroll
    for (int i = 0; i < 4; ++i){
        #pragma unroll
        for (int j = 0; j < 4; ++j){
            int col = c0 + wc + j*16 + m16;
            float bias = Bc[col];
            #pragma unroll
            for (int r = 0; r < 4; ++r){
                int rowg = n0 + wr + i*16 + quad*4 + r;
                if (rowg < N_NODES)
                    Fout[(long)rowg*HIDDEN + col] = f2bf(acc[i][j][r] + bias);
            }
        }
    }
}

// ---- 7. per-column sum / sumsq for BN ----
__global__ void k_stats(const ushort* __restrict__ F, float* __restrict__ stats){
    int c = blockIdx.y*256 + threadIdx.x;   // 0..511
    int r0 = blockIdx.x * 1024;
    int rend = min(r0 + 1024, N_NODES);
    float s = 0.f, ss = 0.f;
    for (int r = r0; r < rend; ++r){
        float v = bf2f(F[(long)r*HIDDEN + c]);
        s += v; ss += v*v;
    }
    atomicAdd(&stats[c], s);
    atomicAdd(&stats[HIDDEN + c], ss);
}

// ---- 8. BN fold: rho_c = gamma*rsqrt(var+eps)*q[c/64]; cvec[o] = sum_k (beta-mu*r)[k*64+o]*q[k]
__global__ void k_solve(const float* __restrict__ stats, const float* __restrict__ gamma,
                        const float* __restrict__ beta, const float* __restrict__ q,
                        float* __restrict__ rho, float* __restrict__ cvec){
    __shared__ float tmp[HIDDEN];
    int c = threadIdx.x;
    const float invN = 1.f / (float)N_NODES;
    float mu  = stats[c] * invN;
    float var = stats[HIDDEN + c] * invN - mu*mu;
    float r = gamma[c] * rsqrtf(var + 1e-5f);
    rho[c] = r * q[c >> 6];
    tmp[c] = beta[c] - mu * r;
    __syncthreads();
    if (c < 64){
        float s = 0.f;
        #pragma unroll
        for (int k = 0; k < 8; ++k) s += tmp[k*64 + c] * q[k];
        cvec[c] = s;
    }
}

// ---- 9. output: out[n,o] = sum_k final[n,k*64+o]*rho[k*64+o] + cvec[o] ----
__global__ void k_out(const ushort* __restrict__ F, const float* __restrict__ rho,
                      const float* __restrict__ cvec, float* __restrict__ out){
    int idx = blockIdx.x*256 + threadIdx.x;
    int n = idx >> 6, o = idx & 63;
    if (n >= N_NODES) return;
    float s = cvec[o];
    #pragma unroll
    for (int k = 0; k < 8; ++k)
        s += bf2f(F[(long)n*HIDDEN + k*64 + o]) * rho[k*64 + o];
    out[idx] = s;
}

extern "C" void kernel_launch(void* const* d_in, const int* in_sizes, int n_in,
                              void* d_out, int out_size, void* d_ws, size_t ws_size,
                              hipStream_t stream) {
    const float* feats = (const float*)d_in[0];
    const int*   src   = (const int*)  d_in[1];
    const int*   dst   = (const int*)  d_in[2];
    const float* W0    = (const float*)d_in[3];
    const float* b0    = (const float*)d_in[4];
    const float* W1    = (const float*)d_in[5];
    const float* b1    = (const float*)d_in[6];
    const float* W2    = (const float*)d_in[7];
    const float* b2    = (const float*)d_in[8];
    const float* fcW   = (const float*)d_in[9];
    const float* fcb   = (const float*)d_in[10];
    const float* gamma = (const float*)d_in[11];
    const float* beta  = (const float*)d_in[12];
    const float* q     = (const float*)d_in[13];
    float* out = (float*)d_out;

    // ---- workspace layout ----
    char* ws = (char*)d_ws;
    size_t off = 0;
    auto alloc = [&](size_t bytes) -> char* {
        char* p = ws + off;
        off = (off + bytes + 511) & ~(size_t)511;
        return p;
    };
    int*    deg     = (int*)   alloc((size_t)N_NODES * 4);
    int*    rowptr  = (int*)   alloc((size_t)N_NODES * 4);
    int*    cursor  = (int*)   alloc((size_t)N_NODES * 4);
    float*  nrm     = (float*) alloc((size_t)N_NODES * 4);
    int*    counter = (int*)   alloc(256);
    int*    csr     = (int*)   alloc((size_t)N_EDGES * 4);
    ushort* H       = (ushort*)alloc((size_t)N_NODES * KDIM * 2);
    ushort* MT      = (ushort*)alloc((size_t)HIDDEN * KDIM * 2);
    float*  Bc      = (float*) alloc((size_t)HIDDEN * 4);
    float*  stats   = (float*) alloc((size_t)2 * HIDDEN * 4);
    float*  rho     = (float*) alloc((size_t)HIDDEN * 4);
    float*  cvec    = (float*) alloc((size_t)64 * 4);
    ushort* Fbuf    = (ushort*)alloc((size_t)N_NODES * HIDDEN * 2);
    (void)ws_size; (void)n_in; (void)in_sizes; (void)out_size;

    hipMemsetAsync(deg, 0, (size_t)N_NODES * 4, stream);
    hipMemsetAsync(counter, 0, 4, stream);
    hipMemsetAsync(stats, 0, (size_t)2 * HIDDEN * 4, stream);

    k_deg    <<<(N_EDGES + 255)/256, 256, 0, stream>>>(dst, deg);
    k_rowptr <<<(N_NODES + 255)/256, 256, 0, stream>>>(deg, rowptr, cursor, nrm, counter);
    k_scatter<<<(N_EDGES + 255)/256, 256, 0, stream>>>(src, dst, cursor, csr);

    int aggGrid = (N_NODES + 3) / 4;
    k_agg<true> <<<aggGrid, 256, 0, stream>>>(feats, 64,  H, 0,   rowptr, deg, nrm, csr);
    k_agg<false><<<aggGrid, 256, 0, stream>>>(H,     192, H, 64,  rowptr, deg, nrm, csr);
    k_agg<false><<<aggGrid, 256, 0, stream>>>(H+64,  192, H, 128, rowptr, deg, nrm, csr);

    k_prepM<<<HIDDEN, KDIM, 0, stream>>>(W0, W1, W2, fcW, MT);
    k_bias <<<2, 256, 0, stream>>>(b0, b1, b2, fcW, fcb, Bc);

    dim3 gGrid((N_NODES + 127)/128, 4);
    k_gemm<<<gGrid, 256, 0, stream>>>(H, MT, Bc, Fbuf);

    dim3 sGrid((N_NODES + 1023)/1024, 2);
    k_stats<<<sGrid, 256, 0, stream>>>(Fbuf, stats);
    k_solve<<<1, HIDDEN, 0, stream>>>(stats, gamma, beta, q, rho, cvec);

    k_out<<<(N_NODES*64 + 255)/256, 256, 0, stream>>>(Fbuf, rho, cvec, out);
}

// Round 2
// 804.870 us; speedup vs baseline: 1.1931x; 1.1931x over previous
//
#include <hip/hip_runtime.h>
#include <hip/hip_bf16.h>
#include <stdint.h>

typedef unsigned short ushort;
typedef unsigned int uint;

#define N_NODES 100000
#define N_EDGES 1600000
#define KDIM 192      // 3 * 64 concatenated h_j
#define HIDDEN 512
#define NCHUNK 782    // ceil(N/128)
#define HTH_BLOCKS 256
#define SDIM (KDIM*KDIM)

typedef __attribute__((ext_vector_type(8))) short short8;
typedef __attribute__((ext_vector_type(4))) short short4v;
typedef __attribute__((ext_vector_type(4))) float float4v;

__device__ __forceinline__ float bf2f(ushort u){
    uint x = ((uint)u) << 16;
    return __builtin_bit_cast(float, x);
}
__device__ __forceinline__ ushort f2bf(float f){
    uint u = __builtin_bit_cast(uint, f);
    u += 0x7fffu + ((u >> 16) & 1u);   // round-to-nearest-even
    return (ushort)(u >> 16);
}

// ---- 1. degree histogram (dst) ----
__global__ void k_deg(const int* __restrict__ dst, int* __restrict__ deg){
    int e = blockIdx.x * 256 + threadIdx.x;
    if (e < N_EDGES) atomicAdd(&deg[dst[e]], 1);
}

// ---- 2. per-node CSR base (block scan + 1 atomic/block), norm ----
__global__ void k_rowptr(const int* __restrict__ deg, int* __restrict__ rowptr,
                         int* __restrict__ cursor, float* __restrict__ nrm,
                         int* __restrict__ counter){
    __shared__ int sc[256];
    __shared__ int sbase;
    int t = threadIdx.x;
    int n = blockIdx.x * 256 + t;
    int d = (n < N_NODES) ? deg[n] : 0;
    sc[t] = d; __syncthreads();
    for (int off = 1; off < 256; off <<= 1){
        int v = 0;
        if (t >= off) v = sc[t - off];
        __syncthreads();
        sc[t] += v;
        __syncthreads();
    }
    int incl = sc[t];
    int total = sc[255];
    int excl = incl - d;
    if (t == 0) sbase = atomicAdd(counter, total);
    __syncthreads();
    if (n < N_NODES){
        int base = sbase + excl;
        rowptr[n] = base;
        cursor[n] = base;
        nrm[n] = rsqrtf((float)(d > 0 ? d : 1));
    }
}

// ---- 3. scatter edges into CSR ----
__global__ void k_scatter(const int* __restrict__ src, const int* __restrict__ dst,
                          int* __restrict__ cursor, int* __restrict__ csr){
    int e = blockIdx.x * 256 + threadIdx.x;
    if (e < N_EDGES){
        int d = dst[e];
        int p = atomicAdd(&cursor[d], 1);
        csr[p] = src[e];
    }
}

// ---- 4. aggregation round ----
template<bool F32>
__global__ void k_agg(const void* __restrict__ inp, long istride,
                      ushort* __restrict__ H, int outoff,
                      const int* __restrict__ rowptr, const int* __restrict__ deg,
                      const float* __restrict__ nrm, const int* __restrict__ csr){
    int node = (blockIdx.x << 2) + (threadIdx.x >> 6);
    int lane = threadIdx.x & 63;
    if (node >= N_NODES) return;
    int beg = rowptr[node];
    int d   = deg[node];
    const float*  inF = (const float*)inp;
    const ushort* inB = (const ushort*)inp;
    float acc = 0.f;
    int i = 0;
    for (; i + 4 <= d; i += 4){
        int s0 = csr[beg+i+0], s1 = csr[beg+i+1], s2 = csr[beg+i+2], s3 = csr[beg+i+3];
        float v0, v1, v2, v3;
        if (F32){
            v0 = inF[(long)s0*istride + lane]; v1 = inF[(long)s1*istride + lane];
            v2 = inF[(long)s2*istride + lane]; v3 = inF[(long)s3*istride + lane];
        } else {
            v0 = bf2f(inB[(long)s0*istride + lane]); v1 = bf2f(inB[(long)s1*istride + lane]);
            v2 = bf2f(inB[(long)s2*istride + lane]); v3 = bf2f(inB[(long)s3*istride + lane]);
        }
        float w0 = nrm[s0], w1 = nrm[s1], w2 = nrm[s2], w3 = nrm[s3];
        acc += w0*v0; acc += w1*v1; acc += w2*v2; acc += w3*v3;
    }
    for (; i < d; ++i){
        int s = csr[beg+i];
        float v = F32 ? inF[(long)s*istride + lane] : bf2f(inB[(long)s*istride + lane]);
        acc += nrm[s] * v;
    }
    H[(long)node*KDIM + outoff + lane] = f2bf(nrm[node] * acc);
}

// ---- 5. fold weights: MT[c][64j+d] = sum_k Wj[k,d] * fcW[c, 512j+k] ----
__global__ void k_prepM(const float* __restrict__ W0, const float* __restrict__ W1,
                        const float* __restrict__ W2, const float* __restrict__ fcW,
                        ushort* __restrict__ MT){
    int c  = blockIdx.x;        // 0..511
    int jd = threadIdx.x;       // 0..191
    int j = jd >> 6, d = jd & 63;
    const float* W  = (j == 0) ? W0 : (j == 1) ? W1 : W2;
    const float* fw = fcW + (long)c*1536 + j*512;
    float s = 0.f;
    #pragma unroll 4
    for (int k = 0; k < 512; ++k) s += W[k*64 + d] * fw[k];
    MT[c*KDIM + jd] = f2bf(s);
}

// ---- 5b. folded bias ----
__global__ void k_bias(const float* __restrict__ b0, const float* __restrict__ b1,
                       const float* __restrict__ b2, const float* __restrict__ fcW,
                       const float* __restrict__ fcb, float* __restrict__ Bc){
    int c = blockIdx.x*256 + threadIdx.x;
    if (c >= HIDDEN) return;
    const float* fw = fcW + (long)c*1536;
    float s = fcb[c];
    for (int k = 0; k < 512; ++k)
        s += b0[k]*fw[k] + b1[k]*fw[512+k] + b2[k]*fw[1024+k];
    Bc[c] = s;
}

// ---- 6. column sums of H (for mean) ----
__global__ void k_colsum(const ushort* __restrict__ H, float* __restrict__ msum){
    int t = threadIdx.x;  // 0..191
    int r0 = blockIdx.x * 391;
    int rend = min(r0 + 391, N_NODES);
    float s = 0.f;
    for (int r = r0; r < rend; ++r) s += bf2f(H[(long)r*KDIM + t]);
    atomicAdd(&msum[t], s);
}

// ---- 7. S = H^T H partials via MFMA, in-LDS transposed staging ----
// Ts[d][n_pair] as uints (lo=even node, hi=odd), bank-swizzled by (d>>2)&15
__global__ __launch_bounds__(256, 2) void k_hth(const ushort* __restrict__ H,
                                                float* __restrict__ P){
    __shared__ uint Ts[KDIM*64];
    int t = threadIdx.x;
    int w = t >> 6, lane = t & 63;
    int m16 = lane & 15, quad = lane >> 4;
    int mband = w * 48;
    float4v acc[3][12] = {};
    for (int chunk = blockIdx.x; chunk < NCHUNK; chunk += HTH_BLOCKS){
        int n0 = chunk * 128;
        #pragma unroll
        for (int pd = 0; pd < 3; ++pd){
            #pragma unroll
            for (int pn = 0; pn < 4; ++pn){
                int rp = (t >> 4) + pn*16;      // row-pair 0..63
                int d4 = pd*64 + (t & 15)*4;
                int gr = n0 + rp*2;
                short4v a = {0,0,0,0}, b = {0,0,0,0};
                if (gr < N_NODES)   a = *(const short4v*)(H + (long)gr*KDIM + d4);
                if (gr+1 < N_NODES) b = *(const short4v*)(H + (long)(gr+1)*KDIM + d4);
                int g = rp >> 2, ws = rp & 3;
                #pragma unroll
                for (int j = 0; j < 4; ++j){
                    int d = d4 + j;
                    uint val = (uint)(ushort)a[j] | ((uint)(ushort)b[j] << 16);
                    Ts[d*64 + (((g ^ ((d>>2)&15)) << 2) | ws)] = val;
                }
            }
        }
        __syncthreads();
        #pragma unroll
        for (int kk = 0; kk < 128; kk += 32){
            int col4 = (kk >> 3) + quad;
            short8 af[3], bf[12];
            #pragma unroll
            for (int i = 0; i < 3; ++i){
                int d = mband + i*16 + m16;
                af[i] = *(const short8*)(Ts + d*64 + ((col4 ^ ((d>>2)&15)) << 2));
            }
            #pragma unroll
            for (int j = 0; j < 12; ++j){
                int d = j*16 + m16;
                bf[j] = *(const short8*)(Ts + d*64 + ((col4 ^ ((d>>2)&15)) << 2));
            }
            #pragma unroll
            for (int i = 0; i < 3; ++i)
                #pragma unroll
                for (int j = 0; j < 12; ++j)
                    acc[i][j] = __builtin_amdgcn_mfma_f32_16x16x32_bf16(af[i], bf[j], acc[i][j], 0,0,0);
        }
        __syncthreads();
    }
    float* Pb = P + (long)blockIdx.x * SDIM;
    #pragma unroll
    for (int i = 0; i < 3; ++i)
        #pragma unroll
        for (int j = 0; j < 12; ++j)
            #pragma unroll
            for (int r = 0; r < 4; ++r){
                int m = mband + i*16 + quad*4 + r;
                int n = j*16 + m16;
                Pb[m*KDIM + n] = acc[i][j][r];
            }
}

// ---- 8. reduce partials -> covariance C = S/N - mean mean^T ----
__global__ void k_reduce(const float* __restrict__ P, const float* __restrict__ msum,
                         float* __restrict__ C){
    int e = blockIdx.x * 256 + threadIdx.x;
    if (e >= SDIM) return;
    float s = 0.f;
    for (int b = 0; b < HTH_BLOCKS; ++b) s += P[(long)b*SDIM + e];
    int d = e / KDIM, dp = e - d*KDIM;
    const float invN = 1.f / (float)N_NODES;
    C[e] = s*invN - (msum[d]*invN)*(msum[dp]*invN);
}

// ---- 9. V[c] = C @ M_c  (uses symmetry of C for coalesced reads) ----
__global__ void k_cv(const float* __restrict__ C, const ushort* __restrict__ MT,
                     float* __restrict__ V){
    int c = blockIdx.x, d = threadIdx.x;  // 512 x 192
    const ushort* mt = MT + c*KDIM;
    float s = 0.f;
    #pragma unroll 4
    for (int dp = 0; dp < KDIM; ++dp)
        s += bf2f(mt[dp]) * C[dp*KDIM + d];
    V[c*KDIM + d] = s;
}

// ---- 10. BN solve: r_c, cvec ----
__global__ void k_solve2(const float* __restrict__ V, const ushort* __restrict__ MT,
                         const float* __restrict__ msum, const float* __restrict__ Bc,
                         const float* __restrict__ gamma, const float* __restrict__ beta,
                         const float* __restrict__ q,
                         float* __restrict__ rr, float* __restrict__ cvec){
    __shared__ float tmp[HIDDEN];
    int c = threadIdx.x;  // 0..511
    const float invN = 1.f / (float)N_NODES;
    float mu = Bc[c], var = 0.f;
    const ushort* mt = MT + c*KDIM;
    const float* vc = V + c*KDIM;
    #pragma unroll 4
    for (int d = 0; d < KDIM; ++d){
        float m = bf2f(mt[d]);
        mu  += msum[d]*invN * m;
        var += vc[d] * m;
    }
    float r = gamma[c] * rsqrtf(var + 1e-5f);
    rr[c] = r;
    tmp[c] = r * (Bc[c] - mu) + beta[c];
    __syncthreads();
    if (c < 64){
        float s = 0.f;
        #pragma unroll
        for (int k = 0; k < 8; ++k) s += q[k] * tmp[k*64 + c];
        cvec[c] = s;
    }
}

// ---- 11. fold rho into M: GT[o][d] = sum_k q_k r_{k64+o} MT[k64+o][d] ----
__global__ void k_buildG(const ushort* __restrict__ MT, const float* __restrict__ rr,
                         const float* __restrict__ q, ushort* __restrict__ GT){
    int o = blockIdx.x, d = threadIdx.x;  // 64 x 192
    float s = 0.f;
    #pragma unroll
    for (int k = 0; k < 8; ++k)
        s += q[k] * rr[k*64 + o] * bf2f(MT[(k*64 + o)*KDIM + d]);
    GT[o*KDIM + d] = f2bf(s);
}

// ---- 12. out = H @ GT^T + cvec ----
#define LDA 200
__global__ __launch_bounds__(256) void k_outgemm(const ushort* __restrict__ H,
                                                 const ushort* __restrict__ GT,
                                                 const float* __restrict__ cvec,
                                                 float* __restrict__ out){
    __shared__ ushort As[128*LDA];
    __shared__ ushort Gs[64*LDA];
    int t = threadIdx.x;
    int n0 = blockIdx.x * 128;
    int w = t >> 6, lane = t & 63;
    int m16 = lane & 15, quad = lane >> 4;
    int wr = w * 32;
    float4v acc[2][4] = {};
    #pragma unroll
    for (int it = 0; it < 12; ++it){
        int flat = it*256 + t;               // 0..3071 = 128 rows * 24 segs
        int row = flat / 24, seg = flat - row*24;
        int gr = n0 + row;
        short8 v = {0,0,0,0,0,0,0,0};
        if (gr < N_NODES) v = *(const short8*)(H + (long)gr*KDIM + seg*8);
        *(short8*)(As + row*LDA + seg*8) = v;
    }
    #pragma unroll
    for (int it = 0; it < 6; ++it){
        int flat = it*256 + t;               // 0..1535 = 64 rows * 24 segs
        int row = flat / 24, seg = flat - row*24;
        short8 v = *(const short8*)(GT + row*KDIM + seg*8);
        *(short8*)(Gs + row*LDA + seg*8) = v;
    }
    __syncthreads();
    #pragma unroll
    for (int kk = 0; kk < 192; kk += 32){
        short8 af[2], bf[4];
        #pragma unroll
        for (int i = 0; i < 2; ++i)
            af[i] = *(const short8*)(As + (wr + i*16 + m16)*LDA + kk + quad*8);
        #pragma unroll
        for (int j = 0; j < 4; ++j)
            bf[j] = *(const short8*)(Gs + (j*16 + m16)*LDA + kk + quad*8);
        #pragma unroll
        for (int i = 0; i < 2; ++i)
            #pragma unroll
            for (int j = 0; j < 4; ++j)
                acc[i][j] = __builtin_amdgcn_mfma_f32_16x16x32_bf16(af[i], bf[j], acc[i][j], 0,0,0);
    }
    #pragma unroll
    for (int i = 0; i < 2; ++i)
        #pragma unroll
        for (int j = 0; j < 4; ++j)
            #pragma unroll
            for (int r = 0; r < 4; ++r){
                int rowg = n0 + wr + i*16 + quad*4 + r;
                int o = j*16 + m16;
                if (rowg < N_NODES) out[(long)rowg*64 + o] = acc[i][j][r] + cvec[o];
            }
}

extern "C" void kernel_launch(void* const* d_in, const int* in_sizes, int n_in,
                              void* d_out, int out_size, void* d_ws, size_t ws_size,
                              hipStream_t stream) {
    const float* feats = (const float*)d_in[0];
    const int*   src   = (const int*)  d_in[1];
    const int*   dst   = (const int*)  d_in[2];
    const float* W0    = (const float*)d_in[3];
    const float* b0    = (const float*)d_in[4];
    const float* W1    = (const float*)d_in[5];
    const float* b1    = (const float*)d_in[6];
    const float* W2    = (const float*)d_in[7];
    const float* b2    = (const float*)d_in[8];
    const float* fcW   = (const float*)d_in[9];
    const float* fcb   = (const float*)d_in[10];
    const float* gamma = (const float*)d_in[11];
    const float* beta  = (const float*)d_in[12];
    const float* q     = (const float*)d_in[13];
    float* out = (float*)d_out;

    char* ws = (char*)d_ws;
    size_t off = 0;
    auto alloc = [&](size_t bytes) -> char* {
        char* p = ws + off;
        off = (off + bytes + 511) & ~(size_t)511;
        return p;
    };
    int*    deg     = (int*)   alloc((size_t)N_NODES * 4);
    int*    rowptr  = (int*)   alloc((size_t)N_NODES * 4);
    int*    cursor  = (int*)   alloc((size_t)N_NODES * 4);
    float*  nrm     = (float*) alloc((size_t)N_NODES * 4);
    int*    counter = (int*)   alloc(256);
    int*    csr     = (int*)   alloc((size_t)N_EDGES * 4);
    ushort* H       = (ushort*)alloc((size_t)N_NODES * KDIM * 2);
    ushort* MT      = (ushort*)alloc((size_t)HIDDEN * KDIM * 2);
    float*  Bc      = (float*) alloc((size_t)HIDDEN * 4);
    float*  msum    = (float*) alloc((size_t)KDIM * 4);
    float*  P       = (float*) alloc((size_t)HTH_BLOCKS * SDIM * 4);
    float*  C       = (float*) alloc((size_t)SDIM * 4);
    float*  V       = (float*) alloc((size_t)HIDDEN * KDIM * 4);
    float*  rr      = (float*) alloc((size_t)HIDDEN * 4);
    float*  cvec    = (float*) alloc((size_t)64 * 4);
    ushort* GT      = (ushort*)alloc((size_t)64 * KDIM * 2);
    (void)ws_size; (void)n_in; (void)in_sizes; (void)out_size;

    hipMemsetAsync(deg, 0, (size_t)N_NODES * 4, stream);
    hipMemsetAsync(counter, 0, 4, stream);
    hipMemsetAsync(msum, 0, (size_t)KDIM * 4, stream);

    k_deg    <<<(N_EDGES + 255)/256, 256, 0, stream>>>(dst, deg);
    k_rowptr <<<(N_NODES + 255)/256, 256, 0, stream>>>(deg, rowptr, cursor, nrm, counter);
    k_scatter<<<(N_EDGES + 255)/256, 256, 0, stream>>>(src, dst, cursor, csr);

    int aggGrid = (N_NODES + 3) / 4;
    k_agg<true> <<<aggGrid, 256, 0, stream>>>(feats, 64,  H, 0,   rowptr, deg, nrm, csr);
    k_agg<false><<<aggGrid, 256, 0, stream>>>(H,     192, H, 64,  rowptr, deg, nrm, csr);
    k_agg<false><<<aggGrid, 256, 0, stream>>>(H+64,  192, H, 128, rowptr, deg, nrm, csr);

    k_prepM<<<HIDDEN, KDIM, 0, stream>>>(W0, W1, W2, fcW, MT);
    k_bias <<<2, 256, 0, stream>>>(b0, b1, b2, fcW, fcb, Bc);

    k_colsum<<<256, KDIM, 0, stream>>>(H, msum);
    k_hth   <<<HTH_BLOCKS, 256, 0, stream>>>(H, P);
    k_reduce<<<(SDIM + 255)/256, 256, 0, stream>>>(P, msum, C);
    k_cv    <<<HIDDEN, KDIM, 0, stream>>>(C, MT, V);
    k_solve2<<<1, HIDDEN, 0, stream>>>(V, MT, msum, Bc, gamma, beta, q, rr, cvec);
    k_buildG<<<64, KDIM, 0, stream>>>(MT, rr, q, GT);

    k_outgemm<<<NCHUNK, 256, 0, stream>>>(H, GT, cvec, out);
}